// Round 15
// baseline (605.950 us; speedup 1.0000x reference)
//
#include <hip/hip_runtime.h>
#include <hip/hip_cooperative_groups.h>

// ---------------------------------------------------------------------------
// AttentionHead: B=4, C=256, N=4096, QK=64. Column-softmax attention.
// R27 = R26 phases FUSED into one cooperative kernel (grid 256 x 1024):
//   phase0 weight-convert (blocks 0..27) -> grid.sync ->
//   phase1 proj (2x 32-pos subtiles per block, 8 waves each) -> grid.sync ->
//   phase2 colsum+fold-rs-into-V -> grid.sync -> phase3 attn+MLP.
// Mechanism: R25 (occupancy x2) and R26 (transpose-pass removal) were both
// NEUTRAL at 197.5us while k_attn is ~85 -> the ~110us remainder is launch
// gaps + per-kernel ramp/tail across 4 serialized dispatches, not kernel
// arithmetic. Fusion removes 3 gaps + 3 ramps (~20-30us) at the cost of
// ~3us/grid-sync. Phase bodies byte-identical to R26 (only thread-mapping
// adapted for proj). __threadfence + grid.sync for cross-XCD visibility.
// Fallback: identical 4-kernel sequence if cooperative launch unavailable.
// ---------------------------------------------------------------------------

namespace cg = cooperative_groups;

typedef unsigned short u16;
typedef __attribute__((ext_vector_type(8))) unsigned short ushort8;
typedef __attribute__((ext_vector_type(2))) unsigned int uint2v;
typedef __attribute__((ext_vector_type(4))) unsigned int uint4v;
typedef __attribute__((ext_vector_type(8))) __bf16 bf16x8;
typedef __attribute__((ext_vector_type(4))) float f32x4;

#define MFMA16(a, b, c) __builtin_amdgcn_mfma_f32_16x16x32_bf16((a), (b), (c), 0, 0, 0)
#define SMEM_BYTES 67584  // 2 x 64 x 264 u16

__device__ __forceinline__ u16 f2bf(float f) {
  unsigned int u = __builtin_bit_cast(unsigned int, f);
  u += 0x7FFFu + ((u >> 16) & 1u);  // round-to-nearest-even
  return (u16)(u >> 16);
}

__device__ __forceinline__ float bf2f(u16 v) {
  return __builtin_bit_cast(float, (unsigned int)v << 16);
}

__device__ __forceinline__ unsigned int cvtpk(float lo, float hi) {
  unsigned int r;
  asm("v_cvt_pk_bf16_f32 %0, %1, %2" : "=v"(r) : "v"(lo), "v"(hi));
  return r;
}

__device__ __forceinline__ bf16x8 ld8(const u16* p) {
  return __builtin_bit_cast(bf16x8, *reinterpret_cast<const ushort8*>(p));
}

__device__ __forceinline__ f32x4 fz4() {
  f32x4 z = {0.f, 0.f, 0.f, 0.f};
  return z;
}

// Fragment-major addressing (u16 units):
//  frag block fb = strip*NK + kchunk; addr = (fb<<9) + lane*8 + e
//  Qf/Kf per batch: 256 istrips x 2 dchunks (NK=2)
//  Vf per batch: 16 cstrips x 128 jchunks (NK=128); weights: O/16 x 8 (NK=8)

// ---- phase 0: weight convert fp32 -> bf16 frag-major (28 id-groups) -------
__device__ __forceinline__ void phase_prep(
    int id, int tid, const float* __restrict__ wq, const float* __restrict__ wk,
    const float* __restrict__ wv, const float* __restrict__ w1,
    const float* __restrict__ w2, u16* __restrict__ dq, u16* __restrict__ dk,
    u16* __restrict__ dv, u16* __restrict__ d1, u16* __restrict__ d2) {
  int fb = id * 16 + (tid >> 6);  // 448 frag blocks total
  int lane = tid & 63;
  const float* src;
  u16* dst;
  int base;
  if (fb < 32)       { src = wq; dst = dq; base = 0; }
  else if (fb < 64)  { src = wk; dst = dk; base = 32; }
  else if (fb < 192) { src = wv; dst = dv; base = 64; }
  else if (fb < 320) { src = w1; dst = d1; base = 192; }
  else               { src = w2; dst = d2; base = 320; }
  int lfb = fb - base;
  int ostrip = lfb >> 3, kk = lfb & 7;
  int l15 = lane & 15, g = lane >> 4;
  const float* s = src + (ostrip * 16 + l15) * 256 + kk * 32 + g * 8;
  f32x4 a0 = *reinterpret_cast<const f32x4*>(s);
  f32x4 a1 = *reinterpret_cast<const f32x4*>(s + 4);
  ushort8 v;
#pragma unroll
  for (int e = 0; e < 4; ++e) { v[e] = f2bf(a0[e]); v[4 + e] = f2bf(a1[e]); }
  *reinterpret_cast<ushort8*>(dst + ((size_t)lfb << 9) + lane * 8) = v;
}

// ---- phase 1: fused transpose+QKV proj; 1024 thr = 2 x (8-wave 32-pos) ----
__device__ __forceinline__ void phase_proj(
    int id, int tid, char* smem, const float* __restrict__ x,
    const u16* __restrict__ wq, const u16* __restrict__ wk,
    const u16* __restrict__ wv, const float* __restrict__ bQ,
    const float* __restrict__ bK, const float* __restrict__ bV,
    const float* __restrict__ PE, u16* __restrict__ Qt, u16* __restrict__ Kt,
    u16* __restrict__ Vc) {
  int b = id & 3, n0base = (id >> 2) * 64;
  int sub = tid >> 9;                 // 0/1: which 32-pos subtile
  float* xLb = (float*)(smem + sub * 33792);  // [256][33] f32 per subtile
  // stage: 512 thr per subtile; thread reads 64B contiguous of one channel
  {
    int tid5 = tid & 511;
    int c2 = tid5 >> 1, half = tid5 & 1;
    int n0 = n0base + sub * 32;
    const float* xp = x + ((size_t)b * 256 + c2) * 4096 + n0 + half * 16;
#pragma unroll
    for (int q = 0; q < 4; ++q) {
      f32x4 v = *reinterpret_cast<const f32x4*>(xp + q * 4);
#pragma unroll
      for (int e = 0; e < 4; ++e) xLb[c2 * 33 + half * 16 + q * 4 + e] = v[e];
    }
  }
  __syncthreads();

  int lane = tid & 63, wid = tid >> 6;   // wid 0..15; sub = wid>>3 (== tid>>9)
  int widp = wid & 7;
  int ph = widp >> 2, w4 = widp & 3;
  int l15 = lane & 15, g = lane >> 4;
  int n0 = n0base + sub * 32;
  int np = n0 + ph * 16;
  int nstrip = (n0 >> 4) + ph;
  int pcol = ph * 16 + l15;

  f32x4 aq = fz4(), ak = fz4(), av[4];
#pragma unroll
  for (int m = 0; m < 4; ++m) av[m] = fz4();

  for (int kk = 0; kk < 8; ++kk) {
    float xv[8];
#pragma unroll
    for (int e = 0; e < 8; ++e) xv[e] = xLb[(kk * 32 + g * 8 + e) * 33 + pcol];
    uint4v xu = {cvtpk(xv[0], xv[1]), cvtpk(xv[2], xv[3]),
                 cvtpk(xv[4], xv[5]), cvtpk(xv[6], xv[7])};
    bf16x8 xa = __builtin_bit_cast(bf16x8, xu);
    bf16x8 fq = ld8(wq + ((w4 * 8 + kk) << 9) + lane * 8);
    bf16x8 fk = ld8(wk + ((w4 * 8 + kk) << 9) + lane * 8);
    aq = MFMA16(xa, fq, aq);
    ak = MFMA16(xa, fk, ak);
    bf16x8 fv[4];
#pragma unroll
    for (int m = 0; m < 4; ++m)
      fv[m] = ld8(wv + (((4 * w4 + m) * 8 + kk) << 9) + lane * 8);
#pragma unroll
    for (int m = 0; m < 4; ++m) av[m] = MFMA16(fv[m], xa, av[m]);
  }

  // Q/K fragment writes: o = 16*w4+l15 (col), pos = np+4g+r (row)
  int o = 16 * w4 + l15;
  int dc = w4 >> 1;                      // o>>5
  int gp = (16 * (w4 & 1) + l15) >> 3;   // (o&31)>>3
  int eo = l15 & 7;                      // o&7
  u16* qf = Qt + (size_t)b * 262144;
  u16* kf = Kt + (size_t)b * 262144;
  {
    f32x4 pe4 = *reinterpret_cast<const f32x4*>(PE + o * 4096 + np + 4 * g);
#pragma unroll
    for (int r = 0; r < 4; ++r) {
      size_t a = (size_t)(((nstrip * 2 + dc) << 9) + ((4 * g + r) + 16 * gp) * 8 + eo);
      qf[a] = f2bf(aq[r] + bQ[o] + pe4[r]);
      kf[a] = f2bf(ak[r] + bK[o] + pe4[r]);
    }
  }
  // V fragment writes: c = 64w4+16m+4g+r (row idx), col = np+l15
  u16* vf = Vc + (size_t)b * 1048576;
  int jchunk = n0 >> 5;
  int vgroup = 2 * ph + (l15 >> 3);
#pragma unroll
  for (int m = 0; m < 4; ++m) {
    int cstrip = 4 * w4 + m;
#pragma unroll
    for (int r = 0; r < 4; ++r) {
      int c15 = 4 * g + r;
      float bvv = bV[64 * w4 + 16 * m + c15];
      size_t a = (size_t)(((cstrip * 128 + jchunk) << 9) +
                          (c15 + 16 * vgroup) * 8 + (l15 & 7));
      vf[a] = f2bf(av[m][r] + bvv);
    }
  }
}

// ---- phase 2: column sums + fold 1/colsum into Vf -------------------------
__device__ __forceinline__ void phase_colsum(int id, int tid, char* smem,
                                             const u16* __restrict__ Qt,
                                             const u16* __restrict__ Kt,
                                             u16* __restrict__ Vc) {
  float* ps = (float*)smem;            // [16][16]
  float* rsf = (float*)(smem + 1024);  // [64]
  int b = id & 3, j0 = (id >> 2) * 64;
  int lane = tid & 63, wid = tid >> 6;  // wid in [0,16)
  int l15 = lane & 15, g = lane >> 4;
  int w4 = wid & 3, iq = wid >> 2;
  const u16* qf = Qt + (size_t)b * 262144;
  const u16* kf = Kt + (size_t)b * 262144;
  int jstrip = (j0 >> 4) + w4;
  bf16x8 fk[2];
#pragma unroll
  for (int h = 0; h < 2; ++h)
    fk[h] = ld8(kf + ((jstrip * 2 + h) << 9) + lane * 8);
  float part = 0.f;
  for (int i0 = iq * 1024; i0 < iq * 1024 + 1024; i0 += 64) {
    f32x4 acc[4];
#pragma unroll
    for (int m = 0; m < 4; ++m) acc[m] = fz4();
#pragma unroll
    for (int m = 0; m < 4; ++m) {
      int ib = ((i0 >> 4) + m) * 2;
      acc[m] = MFMA16(ld8(qf + (ib << 9) + lane * 8), fk[0], acc[m]);
      acc[m] = MFMA16(ld8(qf + ((ib + 1) << 9) + lane * 8), fk[1], acc[m]);
    }
#pragma unroll
    for (int m = 0; m < 4; ++m)
#pragma unroll
      for (int r = 0; r < 4; ++r) part += __expf(acc[m][r] * 0.125f);
  }
  part += __shfl_xor(part, 16);
  part += __shfl_xor(part, 32);
  if (g == 0) ps[wid * 16 + l15] = part;
  __syncthreads();
  if (tid < 64) {
    int jw = tid >> 4, jl = tid & 15;
    rsf[tid] = 1.0f / (ps[jw * 16 + jl] + ps[(jw + 4) * 16 + jl] +
                       ps[(jw + 8) * 16 + jl] + ps[(jw + 12) * 16 + jl]);
  }
  __syncthreads();
  // scale Vf for j in [j0, j0+64), all 256 channels (4 threads / channel)
  {
    int c = tid >> 2, q4 = tid & 3;
    int cstrip = c >> 4, c15 = c & 15;
    u16* vb2 = Vc + (size_t)b * 1048576;
#pragma unroll
    for (int s = 0; s < 2; ++s) {
      int joo = q4 * 16 + s * 8;
      int jc = (j0 + joo) >> 5;
      int jg = (joo & 31) >> 3;
      u16* p = vb2 + (((size_t)(cstrip * 128 + jc)) << 9) + (c15 + 16 * jg) * 8;
      ushort8 v = *reinterpret_cast<const ushort8*>(p);
      ushort8 ov;
#pragma unroll
      for (int e = 0; e < 8; ++e) ov[e] = f2bf(bf2f(v[e]) * rsf[joo + e]);
      *reinterpret_cast<ushort8*>(p) = ov;
    }
  }
}

// ---- phase 3: attention + fused MLP ---------------------------------------
__device__ __forceinline__ void phase_attn(
    int id, int tid, char* smem, const u16* __restrict__ Qt,
    const u16* __restrict__ Kt, const u16* __restrict__ Vc,
    const u16* __restrict__ w1, const float* __restrict__ b1,
    const u16* __restrict__ w2, const float* __restrict__ b2,
    const float* __restrict__ x, float* __restrict__ out) {
  u16 (*P0)[264] = (u16 (*)[264])smem;            // dbuf half 0 / att tile
  u16 (*P1)[264] = (u16 (*)[264])(smem + 33792);  // dbuf half 1 / hdn tile
  int b = id & 3, i0 = (id >> 2) * 64;
  int lane = tid & 63, wid = tid >> 6;  // wid in [0,16)
  int l15 = lane & 15, g = lane >> 4;
  int ih = wid >> 3, cw = wid & 7;  // PV tile: i-half, 32-c strip
  const u16* qf = Qt + (size_t)b * 262144;
  const u16* kf = Kt + (size_t)b * 262144;
  const u16* vf = Vc + (size_t)b * 1048576;

  bf16x8 aq[4][2];
#pragma unroll
  for (int m = 0; m < 4; ++m)
#pragma unroll
    for (int h = 0; h < 2; ++h)
      aq[m][h] = ld8(qf + ((((i0 >> 4) + m) * 2 + h) << 9) + lane * 8);

  f32x4 oacc[2][2];  // [m][cs]: i = i0+32ih+16m+4g+r, c = 32cw+16cs+l15
#pragma unroll
  for (int m = 0; m < 2; ++m)
#pragma unroll
    for (int cs = 0; cs < 2; ++cs) oacc[m][cs] = fz4();

  const u16* kl = kf + lane * 8;
  bf16x8 fk0 = ld8(kl + ((wid * 2 + 0) << 9));
  bf16x8 fk1 = ld8(kl + ((wid * 2 + 1) << 9));

  auto S_phase = [&](int j0, u16 (*Pb)[264]) {
    f32x4 s[4];
#pragma unroll
    for (int m = 0; m < 4; ++m) {
      s[m] = fz4();
      s[m] = MFMA16(fk0, aq[m][0], s[m]);
      s[m] = MFMA16(fk1, aq[m][1], s[m]);
    }
#pragma unroll
    for (int m = 0; m < 4; ++m) {
      float e0 = __expf(s[m][0] * 0.125f);
      float e1 = __expf(s[m][1] * 0.125f);
      float e2 = __expf(s[m][2] * 0.125f);
      float e3 = __expf(s[m][3] * 0.125f);
      uint2v w = {cvtpk(e0, e1), cvtpk(e2, e3)};
      *reinterpret_cast<uint2v*>(&Pb[16 * m + l15][16 * wid + 4 * g]) = w;
    }
    if (j0 < 3840) {
      int jstrip = ((j0 + 256) >> 4) + wid;
      fk0 = ld8(kl + ((jstrip * 2 + 0) << 9));
      fk1 = ld8(kl + ((jstrip * 2 + 1) << 9));
    }
  };
  auto PV_phase = [&](int j0, u16 (*Pb)[264], const bf16x8 (&fvp)[2][4]) {
    __builtin_amdgcn_s_setprio(1);
#pragma unroll
    for (int h = 0; h < 8; ++h) {
      bf16x8 ap[2];
#pragma unroll
      for (int m = 0; m < 2; ++m)
        ap[m] = ld8(&Pb[32 * ih + 16 * m + l15][h * 32 + 8 * g]);
      bf16x8 f0, f1;
      if (h < 4) {
        f0 = fvp[0][h];
        f1 = fvp[1][h];
      } else {
        f0 = ld8(vf + (((2 * cw + 0) * 128 + (j0 >> 5) + h) << 9) + lane * 8);
        f1 = ld8(vf + (((2 * cw + 1) * 128 + (j0 >> 5) + h) << 9) + lane * 8);
      }
      oacc[0][0] = MFMA16(ap[0], f0, oacc[0][0]);
      oacc[0][1] = MFMA16(ap[0], f1, oacc[0][1]);
      oacc[1][0] = MFMA16(ap[1], f0, oacc[1][0]);
      oacc[1][1] = MFMA16(ap[1], f1, oacc[1][1]);
    }
    __builtin_amdgcn_s_setprio(0);
  };

  S_phase(0, P0);
  int buf = 0;
  for (int t = 0; t < 16; ++t) {
    __syncthreads();
    int j0 = t * 256;
    u16 (*Pcur)[264] = buf ? P1 : P0;
    u16 (*Pnxt)[264] = buf ? P0 : P1;
    bf16x8 fvp[2][4];
#pragma unroll
    for (int cs = 0; cs < 2; ++cs)
#pragma unroll
      for (int h = 0; h < 4; ++h)
        fvp[cs][h] = ld8(vf + (((2 * cw + cs) * 128 + (j0 >> 5) + h) << 9) + lane * 8);
    if (wid & 1) {
      if (t < 15) S_phase(j0 + 256, Pnxt);
      PV_phase(j0, Pcur, fvp);
    } else {
      PV_phase(j0, Pcur, fvp);
      if (t < 15) S_phase(j0 + 256, Pnxt);
    }
    buf ^= 1;
  }

  // ---- fused MLP on the block's 64x256 tile ----
  u16 (*attL)[264] = P0;
  u16 (*hdnL)[264] = P1;
  __syncthreads();
#pragma unroll
  for (int m = 0; m < 2; ++m)
#pragma unroll
    for (int cs = 0; cs < 2; ++cs)
#pragma unroll
      for (int r = 0; r < 4; ++r)
        attL[32 * ih + 16 * m + 4 * g + r][32 * cw + 16 * cs + l15] =
            f2bf(oacc[m][cs][r]);
  __syncthreads();

  // stage 1: hdn = mish(att @ W1^T + b1); wave strip = 16 h (ostrip = wid)
  {
    f32x4 acc1[4];
#pragma unroll
    for (int m = 0; m < 4; ++m) acc1[m] = fz4();
    for (int kk = 0; kk < 8; ++kk) {
      bf16x8 bn = ld8(w1 + ((wid * 8 + kk) << 9) + lane * 8);
#pragma unroll
      for (int m = 0; m < 4; ++m) {
        bf16x8 am = ld8(&attL[16 * m + l15][kk * 32 + 8 * g]);
        acc1[m] = MFMA16(am, bn, acc1[m]);
      }
    }
    float bb = b1[16 * wid + l15];
#pragma unroll
    for (int m = 0; m < 4; ++m)
#pragma unroll
      for (int r = 0; r < 4; ++r) {
        float v = acc1[m][r] + bb;
        float sp = (v > 15.f) ? v : __logf(1.f + __expf(v));
        float e2 = __expf(-2.f * sp);
        float th = (1.f - e2) / (1.f + e2);
        hdnL[16 * m + 4 * g + r][16 * wid + l15] = f2bf(v * th);
      }
  }
  __syncthreads();

  // stage 2: out = hdn @ W2^T + b2 + x; wave strip = 16 o (ostrip = wid)
  {
    f32x4 acc2[4];
#pragma unroll
    for (int n = 0; n < 4; ++n) acc2[n] = fz4();
    for (int kk = 0; kk < 8; ++kk) {
      bf16x8 am = ld8(w2 + ((wid * 8 + kk) << 9) + lane * 8);
#pragma unroll
      for (int n = 0; n < 4; ++n) {
        bf16x8 bn = ld8(&hdnL[16 * n + l15][kk * 32 + 8 * g]);
        acc2[n] = MFMA16(am, bn, acc2[n]);
      }
    }
    f32x4 b2v = *reinterpret_cast<const f32x4*>(b2 + 16 * wid + 4 * g);
#pragma unroll
    for (int r = 0; r < 4; ++r) {
      int o = 16 * wid + 4 * g + r;
#pragma unroll
      for (int n = 0; n < 4; ++n) {
        int pos = i0 + 16 * n + l15;
        size_t idx = ((size_t)b * 256 + o) * 4096 + pos;
        out[idx] = acc2[n][r] + b2v[r] + x[idx];
      }
    }
  }
}

// ---- cooperative mega-kernel ----------------------------------------------
__global__ __launch_bounds__(1024, 4) void k_fused(
    const float* __restrict__ x, const float* __restrict__ WQ,
    const float* __restrict__ WK, const float* __restrict__ WV,
    const float* __restrict__ W1, const float* __restrict__ W2,
    const float* __restrict__ bQ, const float* __restrict__ bK,
    const float* __restrict__ bV, const float* __restrict__ PE,
    const float* __restrict__ b1, const float* __restrict__ b2,
    float* __restrict__ out, u16* __restrict__ Qt, u16* __restrict__ Kt,
    u16* __restrict__ Vc, u16* __restrict__ wqB, u16* __restrict__ wkB,
    u16* __restrict__ wvB, u16* __restrict__ w1B, u16* __restrict__ w2B) {
  __shared__ char smem[SMEM_BYTES];
  cg::grid_group grid = cg::this_grid();
  int id = blockIdx.x, tid = threadIdx.x;

  if (id < 28) phase_prep(id, tid, WQ, WK, WV, W1, W2, wqB, wkB, wvB, w1B, w2B);
  __threadfence();
  grid.sync();

  phase_proj(id, tid, smem, x, wqB, wkB, wvB, bQ, bK, bV, PE, Qt, Kt, Vc);
  __threadfence();
  grid.sync();

  phase_colsum(id, tid, smem, Qt, Kt, Vc);
  __threadfence();
  grid.sync();

  phase_attn(id, tid, smem, Qt, Kt, Vc, w1B, b1, w2B, b2, x, out);
}

// ---- fallback standalone kernels (identical phase bodies) -----------------
__global__ __launch_bounds__(1024) void k_prep(
    const float* __restrict__ wq, const float* __restrict__ wk,
    const float* __restrict__ wv, const float* __restrict__ w1,
    const float* __restrict__ w2, u16* __restrict__ dq, u16* __restrict__ dk,
    u16* __restrict__ dv, u16* __restrict__ d1, u16* __restrict__ d2) {
  phase_prep(blockIdx.x, threadIdx.x, wq, wk, wv, w1, w2, dq, dk, dv, d1, d2);
}

__global__ __launch_bounds__(1024) void k_proj(
    const float* __restrict__ x, const u16* __restrict__ wq,
    const u16* __restrict__ wk, const u16* __restrict__ wv,
    const float* __restrict__ bQ, const float* __restrict__ bK,
    const float* __restrict__ bV, const float* __restrict__ PE,
    u16* __restrict__ Qt, u16* __restrict__ Kt, u16* __restrict__ Vc) {
  __shared__ char smem[SMEM_BYTES];
  phase_proj(blockIdx.x, threadIdx.x, smem, x, wq, wk, wv, bQ, bK, bV, PE, Qt, Kt, Vc);
}

__global__ __launch_bounds__(1024) void k_colsum(const u16* __restrict__ Qt,
                                                 const u16* __restrict__ Kt,
                                                 u16* __restrict__ Vc) {
  __shared__ char smem[2048];
  phase_colsum(blockIdx.x, threadIdx.x, smem, Qt, Kt, Vc);
}

__global__ __launch_bounds__(1024, 4) void k_attn(
    const u16* __restrict__ Qt, const u16* __restrict__ Kt,
    const u16* __restrict__ Vc, const u16* __restrict__ w1,
    const float* __restrict__ b1, const u16* __restrict__ w2,
    const float* __restrict__ b2, const float* __restrict__ x,
    float* __restrict__ out) {
  __shared__ char smem[SMEM_BYTES];
  phase_attn(blockIdx.x, threadIdx.x, smem, Qt, Kt, Vc, w1, b1, w2, b2, x, out);
}

// ---- workspace layout (bytes) ---------------------------------------------
#define WS_QT 8388608u    //  2,097,152  Qf  [4][256*2][64][8] bf16
#define WS_KT 10485760u   //  2,097,152  Kf  [4][256*2][64][8] bf16
#define WS_VC 12582912u   //  8,388,608  Vf  [4][16*128][64][8] bf16
#define WS_WQ 21037056u   //     32,768  wqf [4*8][64][8]
#define WS_WK 21069824u   //     32,768
#define WS_WV 21102592u   //    131,072  wvf [16*8][64][8]
#define WS_W1 21233664u   //    131,072
#define WS_W2 21364736u   //    131,072   (end: 21,495,808 < 29,884,416)

extern "C" void kernel_launch(void* const* d_in, const int* in_sizes, int n_in,
                              void* d_out, int out_size, void* d_ws, size_t ws_size,
                              hipStream_t stream) {
  (void)in_sizes; (void)n_in; (void)out_size; (void)ws_size;
  const float* x  = (const float*)d_in[0];
  const float* WQ = (const float*)d_in[1];
  const float* bQ = (const float*)d_in[2];
  const float* WK = (const float*)d_in[3];
  const float* bK = (const float*)d_in[4];
  const float* WV = (const float*)d_in[5];
  const float* bV = (const float*)d_in[6];
  const float* PE = (const float*)d_in[7];
  const float* W1 = (const float*)d_in[8];
  const float* b1 = (const float*)d_in[9];
  const float* W2 = (const float*)d_in[10];
  const float* b2 = (const float*)d_in[11];
  float* out = (float*)d_out;
  char* ws = (char*)d_ws;

  u16* Qt   = (u16*)(ws + WS_QT);
  u16* Kt   = (u16*)(ws + WS_KT);
  u16* Vc   = (u16*)(ws + WS_VC);
  u16* wqB  = (u16*)(ws + WS_WQ);
  u16* wkB  = (u16*)(ws + WS_WK);
  u16* wvB  = (u16*)(ws + WS_WV);
  u16* w1B  = (u16*)(ws + WS_W1);
  u16* w2B  = (u16*)(ws + WS_W2);

  int dev = 0, coop = 0;
  hipGetDevice(&dev);
  hipDeviceGetAttribute(&coop, hipDeviceAttributeCooperativeLaunch, dev);
  if (coop) {
    void* args[] = {(void*)&x,  (void*)&WQ, (void*)&WK, (void*)&WV, (void*)&W1,
                    (void*)&W2, (void*)&bQ, (void*)&bK, (void*)&bV, (void*)&PE,
                    (void*)&b1, (void*)&b2, (void*)&out, (void*)&Qt, (void*)&Kt,
                    (void*)&Vc, (void*)&wqB, (void*)&wkB, (void*)&wvB,
                    (void*)&w1B, (void*)&w2B};
    hipError_t e = hipLaunchCooperativeKernel((const void*)k_fused, dim3(256),
                                              dim3(1024), args, 0, stream);
    if (e == hipSuccess) return;
    (void)hipGetLastError();  // clear sticky error, fall through
  }
  k_prep<<<28, 1024, 0, stream>>>(WQ, WK, WV, W1, W2, wqB, wkB, wvB, w1B, w2B);
  k_proj<<<256, 1024, 0, stream>>>(x, wqB, wkB, wvB, bQ, bK, bV, PE, Qt, Kt, Vc);
  k_colsum<<<256, 1024, 0, stream>>>(Qt, Kt, Vc);
  k_attn<<<256, 1024, 0, stream>>>(Qt, Kt, Vc, w1B, b1, w2B, b2, x, out);
}

// Round 16
// 196.213 us; speedup vs baseline: 3.0882x; 3.0882x over previous
//
#include <hip/hip_runtime.h>

// ---------------------------------------------------------------------------
// AttentionHead: B=4, C=256, N=4096, QK=64. Column-softmax attention.
// R28 = R24 VERBATIM (best harness-verified: 196.76us). Recovery from R27's
// cooperative-fusion catastrophe (grid.sync ~100us+/sync at 256x1024 across
// 8 non-coherent XCDs; 515us single dispatch).
// Session ledger: R19 frag-major coalescing (-62us, gather-serialization
// mechanism confirmed), R21 stagger (-4us), R24 MLP fusion (-13us). R25
// occupancy x2 / R26 transpose-elim / R27 coop fusion: neutral or worse ->
// remaining ~110us is distributed real work (colsum's duplicated QK^T,
// proj staging+scatter epilogue), not launch overhead.
// ---------------------------------------------------------------------------

typedef unsigned short u16;
typedef __attribute__((ext_vector_type(8))) unsigned short ushort8;
typedef __attribute__((ext_vector_type(2))) unsigned int uint2v;
typedef __attribute__((ext_vector_type(8))) __bf16 bf16x8;
typedef __attribute__((ext_vector_type(4))) float f32x4;

#define MFMA16(a, b, c) __builtin_amdgcn_mfma_f32_16x16x32_bf16((a), (b), (c), 0, 0, 0)

__device__ __forceinline__ u16 f2bf(float f) {
  unsigned int u = __builtin_bit_cast(unsigned int, f);
  u += 0x7FFFu + ((u >> 16) & 1u);  // round-to-nearest-even
  return (u16)(u >> 16);
}

__device__ __forceinline__ float bf2f(u16 v) {
  return __builtin_bit_cast(float, (unsigned int)v << 16);
}

__device__ __forceinline__ unsigned int cvtpk(float lo, float hi) {
  unsigned int r;
  asm("v_cvt_pk_bf16_f32 %0, %1, %2" : "=v"(r) : "v"(lo), "v"(hi));
  return r;
}

__device__ __forceinline__ bf16x8 ld8(const u16* p) {
  return __builtin_bit_cast(bf16x8, *reinterpret_cast<const ushort8*>(p));
}

__device__ __forceinline__ f32x4 fz4() {
  f32x4 z = {0.f, 0.f, 0.f, 0.f};
  return z;
}

// Fragment-major addressing (u16 units):
//  frag block fb = strip*NK + kchunk; addr = (fb<<9) + lane*8 + e
//  lane = idx15 + 16*g holds tensor[idx = strip*16 + idx15][k = kchunk*32 + g*8 + e]
//  Qf/Kf per batch: 256 istrips x 2 dchunks (NK=2); xTf: 256 x 8 (NK=8)
//  Vf per batch: 16 cstrips x 128 jchunks (NK=128); weights: O/16 x 8 (NK=8)

// ---- fused prep: transpose (blocks 0..1023) + weight convert (1024..1135) -
__global__ __launch_bounds__(256) void k_prep(
    const float* __restrict__ x, const float* __restrict__ wq,
    const float* __restrict__ wk, const float* __restrict__ wv,
    const float* __restrict__ w1, const float* __restrict__ w2,
    u16* __restrict__ xT, u16* __restrict__ dq, u16* __restrict__ dk,
    u16* __restrict__ dv, u16* __restrict__ d1, u16* __restrict__ d2) {
  __shared__ float t[64][65];
  int id = blockIdx.x;
  if (id < 1024) {
    int n0 = (id & 63) * 64, c0 = ((id >> 6) & 3) * 64, b = id >> 8;
    int tx = threadIdx.x & 63, ty = threadIdx.x >> 6;
    const float* xb = x + ((size_t)b * 256 + c0) * 4096 + n0;
#pragma unroll
    for (int i = 0; i < 64; i += 4) t[ty + i][tx] = xb[(size_t)(ty + i) * 4096 + tx];
    __syncthreads();
    int lane = tx, w = ty;
    int l15 = lane & 15, g = lane >> 4;
    u16* xob = xT + (size_t)b * 1048576;
    int nstrip = (n0 >> 4) + w;
#pragma unroll
    for (int q = 0; q < 2; ++q) {
      int kk = (c0 >> 5) + q;
      int cl = q * 32 + g * 8;
      ushort8 v;
#pragma unroll
      for (int e = 0; e < 8; ++e) v[e] = f2bf(t[cl + e][w * 16 + l15]);
      *reinterpret_cast<ushort8*>(xob + ((size_t)(nstrip * 8 + kk) << 9) + lane * 8) = v;
    }
  } else {
    int tt = (id - 1024) * 256 + threadIdx.x;
    int lane = tt & 63, fb = tt >> 6;  // 448 frag blocks total
    const float* src;
    u16* dst;
    int base;
    if (fb < 32)       { src = wq; dst = dq; base = 0; }
    else if (fb < 64)  { src = wk; dst = dk; base = 32; }
    else if (fb < 192) { src = wv; dst = dv; base = 64; }
    else if (fb < 320) { src = w1; dst = d1; base = 192; }
    else               { src = w2; dst = d2; base = 320; }
    int lfb = fb - base;
    int ostrip = lfb >> 3, kk = lfb & 7;
    int l15 = lane & 15, g = lane >> 4;
    const float* s = src + (ostrip * 16 + l15) * 256 + kk * 32 + g * 8;
    f32x4 a0 = *reinterpret_cast<const f32x4*>(s);
    f32x4 a1 = *reinterpret_cast<const f32x4*>(s + 4);
    ushort8 v;
#pragma unroll
    for (int e = 0; e < 4; ++e) { v[e] = f2bf(a0[e]); v[4 + e] = f2bf(a1[e]); }
    *reinterpret_cast<ushort8*>(dst + ((size_t)lfb << 9) + lane * 8) = v;
  }
}

// ---- fused QKV projection: 32-pos tiles, grid 512 linear (b = id&3) -------
__global__ __launch_bounds__(256) void k_proj(
    const u16* __restrict__ xT, const u16* __restrict__ wq,
    const u16* __restrict__ wk, const u16* __restrict__ wv,
    const float* __restrict__ bQ, const float* __restrict__ bK,
    const float* __restrict__ bV, const float* __restrict__ PE,
    u16* __restrict__ Qt, u16* __restrict__ Kt, u16* __restrict__ Vc) {
  int b = blockIdx.x & 3, n0 = (blockIdx.x >> 2) * 32;
  int lane = threadIdx.x & 63, wid = threadIdx.x >> 6;
  int l15 = lane & 15, g = lane >> 4;
  const u16* xf = xT + (size_t)b * 1048576;

  f32x4 aq[2], ak[2], av[4][2];
#pragma unroll
  for (int m = 0; m < 2; ++m) { aq[m] = fz4(); ak[m] = fz4(); }
#pragma unroll
  for (int m = 0; m < 4; ++m)
#pragma unroll
    for (int n = 0; n < 2; ++n) av[m][n] = fz4();

  for (int kk = 0; kk < 8; ++kk) {
    bf16x8 xa[2];
#pragma unroll
    for (int m = 0; m < 2; ++m)
      xa[m] = ld8(xf + ((((n0 >> 4) + m) * 8 + kk) << 9) + lane * 8);
    bf16x8 fq = ld8(wq + ((wid * 8 + kk) << 9) + lane * 8);
    bf16x8 fk = ld8(wk + ((wid * 8 + kk) << 9) + lane * 8);
#pragma unroll
    for (int m = 0; m < 2; ++m) {
      aq[m] = MFMA16(xa[m], fq, aq[m]);
      ak[m] = MFMA16(xa[m], fk, ak[m]);
    }
    bf16x8 fv[4];
#pragma unroll
    for (int m = 0; m < 4; ++m)
      fv[m] = ld8(wv + (((4 * wid + m) * 8 + kk) << 9) + lane * 8);
#pragma unroll
    for (int m = 0; m < 4; ++m)
#pragma unroll
      for (int n = 0; n < 2; ++n) av[m][n] = MFMA16(fv[m], xa[n], av[m][n]);
  }

  // Q/K fragment writes: o = 16*wid+l15 (col), pos = n0+16m+4g+r (row)
  int o = 16 * wid + l15;
  int dc = wid >> 1;                      // o>>5
  int gp = (16 * (wid & 1) + l15) >> 3;   // (o&31)>>3
  int eo = l15 & 7;                       // o&7
  u16* qf = Qt + (size_t)b * 262144;
  u16* kf = Kt + (size_t)b * 262144;
#pragma unroll
  for (int m = 0; m < 2; ++m) {
    int istrip = (n0 >> 4) + m;
    f32x4 pe4 = *reinterpret_cast<const f32x4*>(PE + o * 4096 + n0 + 16 * m + 4 * g);
#pragma unroll
    for (int r = 0; r < 4; ++r) {
      size_t a = (size_t)(((istrip * 2 + dc) << 9) + ((4 * g + r) + 16 * gp) * 8 + eo);
      qf[a] = f2bf(aq[m][r] + bQ[o] + pe4[r]);
      kf[a] = f2bf(ak[m][r] + bK[o] + pe4[r]);
    }
  }
  // V fragment writes: c = 64wid+16m+4g+r (row idx), pos = n0+16n+l15 (col k)
  u16* vf = Vc + (size_t)b * 1048576;
  int jchunk = n0 >> 5;
#pragma unroll
  for (int m = 0; m < 4; ++m) {
    int cstrip = 4 * wid + m;
#pragma unroll
    for (int r = 0; r < 4; ++r) {
      int c15 = 4 * g + r;
      float bvv = bV[64 * wid + 16 * m + c15];
#pragma unroll
      for (int n = 0; n < 2; ++n) {
        size_t a = (size_t)(((cstrip * 128 + jchunk) << 9) +
                            (c15 + 16 * (2 * n + (l15 >> 3))) * 8 + (l15 & 7));
        vf[a] = f2bf(av[m][n][r] + bvv);
      }
    }
  }
}

// ---- pass 1: column sums + fold 1/colsum into Vf, 512 thr, grid 256 -------
__global__ __launch_bounds__(512) void k_colsum(const u16* __restrict__ Qt,
                                                const u16* __restrict__ Kt,
                                                u16* __restrict__ Vc) {
  __shared__ float ps[8][16];
  __shared__ float rsf[64];
  int b = blockIdx.x & 3, j0 = (blockIdx.x >> 2) * 64;
  int lane = threadIdx.x & 63, wid = threadIdx.x >> 6;  // wid in [0,8)
  int l15 = lane & 15, g = lane >> 4;
  int w4 = wid & 3, ihalf = wid >> 2;
  const u16* qf = Qt + (size_t)b * 262144;
  const u16* kf = Kt + (size_t)b * 262144;
  int jstrip = (j0 >> 4) + w4;
  bf16x8 fk[2];
#pragma unroll
  for (int h = 0; h < 2; ++h)
    fk[h] = ld8(kf + ((jstrip * 2 + h) << 9) + lane * 8);
  float part = 0.f;
  for (int i0 = ihalf * 2048; i0 < ihalf * 2048 + 2048; i0 += 64) {
    f32x4 acc[4];
#pragma unroll
    for (int m = 0; m < 4; ++m) acc[m] = fz4();
#pragma unroll
    for (int m = 0; m < 4; ++m) {
      int ib = ((i0 >> 4) + m) * 2;
      acc[m] = MFMA16(ld8(qf + (ib << 9) + lane * 8), fk[0], acc[m]);
      acc[m] = MFMA16(ld8(qf + ((ib + 1) << 9) + lane * 8), fk[1], acc[m]);
    }
#pragma unroll
    for (int m = 0; m < 4; ++m)
#pragma unroll
      for (int r = 0; r < 4; ++r) part += __expf(acc[m][r] * 0.125f);
  }
  part += __shfl_xor(part, 16);
  part += __shfl_xor(part, 32);
  if (g == 0) ps[wid][l15] = part;
  __syncthreads();
  if (threadIdx.x < 64) {
    int jj = threadIdx.x;
    rsf[jj] = 1.0f / (ps[jj >> 4][jj & 15] + ps[(jj >> 4) + 4][jj & 15]);
  }
  __syncthreads();
  // scale Vf for j in [j0, j0+64), all 256 channels (2 threads / channel)
  {
    int c = threadIdx.x >> 1, half = threadIdx.x & 1;
    int cstrip = c >> 4, c15 = c & 15;
    u16* vb2 = Vc + (size_t)b * 1048576;
#pragma unroll
    for (int q = 0; q < 2; ++q) {
      int jo = half * 32 + q * 16;
#pragma unroll
      for (int s = 0; s < 2; ++s) {
        int joo = jo + s * 8;
        int jc = (j0 + joo) >> 5;
        int jg = (joo & 31) >> 3;
        u16* p = vb2 + (((size_t)(cstrip * 128 + jc)) << 9) + (c15 + 16 * jg) * 8;
        ushort8 v = *reinterpret_cast<const ushort8*>(p);
        ushort8 ov;
#pragma unroll
        for (int e = 0; e < 8; ++e) ov[e] = f2bf(bf2f(v[e]) * rsf[joo + e]);
        *reinterpret_cast<ushort8*>(p) = ov;
      }
    }
  }
}

// ---- pass 2: attention + fused MLP, 1024 thr, grid 256 (b = id&3) ---------
__global__ __launch_bounds__(1024, 4) void k_attn(
    const u16* __restrict__ Qt, const u16* __restrict__ Kt,
    const u16* __restrict__ Vc, const u16* __restrict__ w1,
    const float* __restrict__ b1, const u16* __restrict__ w2,
    const float* __restrict__ b2, const float* __restrict__ x,
    float* __restrict__ out) {
  __shared__ u16 P[2][64][264];  // dbuf; reused as att/hdn tiles for MLP
  int b = blockIdx.x & 3, i0 = (blockIdx.x >> 2) * 64;
  int lane = threadIdx.x & 63, wid = threadIdx.x >> 6;  // wid in [0,16)
  int l15 = lane & 15, g = lane >> 4;
  int ih = wid >> 3, cw = wid & 7;  // PV tile: i-half, 32-c strip
  const u16* qf = Qt + (size_t)b * 262144;
  const u16* kf = Kt + (size_t)b * 262144;
  const u16* vf = Vc + (size_t)b * 1048576;

  bf16x8 aq[4][2];
#pragma unroll
  for (int m = 0; m < 4; ++m)
#pragma unroll
    for (int h = 0; h < 2; ++h)
      aq[m][h] = ld8(qf + ((((i0 >> 4) + m) * 2 + h) << 9) + lane * 8);

  f32x4 oacc[2][2];  // [m][cs]: i = i0+32ih+16m+4g+r, c = 32cw+16cs+l15
#pragma unroll
  for (int m = 0; m < 2; ++m)
#pragma unroll
    for (int cs = 0; cs < 2; ++cs) oacc[m][cs] = fz4();

  const u16* kl = kf + lane * 8;
  bf16x8 fk0 = ld8(kl + ((wid * 2 + 0) << 9));
  bf16x8 fk1 = ld8(kl + ((wid * 2 + 1) << 9));

  auto S_phase = [&](int j0, int sbuf) {
    f32x4 s[4];
#pragma unroll
    for (int m = 0; m < 4; ++m) {
      s[m] = fz4();
      s[m] = MFMA16(fk0, aq[m][0], s[m]);
      s[m] = MFMA16(fk1, aq[m][1], s[m]);
    }
#pragma unroll
    for (int m = 0; m < 4; ++m) {
      float e0 = __expf(s[m][0] * 0.125f);
      float e1 = __expf(s[m][1] * 0.125f);
      float e2 = __expf(s[m][2] * 0.125f);
      float e3 = __expf(s[m][3] * 0.125f);
      uint2v w = {cvtpk(e0, e1), cvtpk(e2, e3)};
      *reinterpret_cast<uint2v*>(&P[sbuf][16 * m + l15][16 * wid + 4 * g]) = w;
    }
    if (j0 < 3840) {
      int jstrip = ((j0 + 256) >> 4) + wid;
      fk0 = ld8(kl + ((jstrip * 2 + 0) << 9));
      fk1 = ld8(kl + ((jstrip * 2 + 1) << 9));
    }
  };
  auto PV_phase = [&](int j0, int pbuf, const bf16x8 (&fvp)[2][4]) {
    __builtin_amdgcn_s_setprio(1);
#pragma unroll
    for (int h = 0; h < 8; ++h) {
      bf16x8 ap[2];
#pragma unroll
      for (int m = 0; m < 2; ++m)
        ap[m] = ld8(&P[pbuf][32 * ih + 16 * m + l15][h * 32 + 8 * g]);
      bf16x8 f0, f1;
      if (h < 4) {
        f0 = fvp[0][h];
        f1 = fvp[1][h];
      } else {
        f0 = ld8(vf + (((2 * cw + 0) * 128 + (j0 >> 5) + h) << 9) + lane * 8);
        f1 = ld8(vf + (((2 * cw + 1) * 128 + (j0 >> 5) + h) << 9) + lane * 8);
      }
      oacc[0][0] = MFMA16(ap[0], f0, oacc[0][0]);
      oacc[0][1] = MFMA16(ap[0], f1, oacc[0][1]);
      oacc[1][0] = MFMA16(ap[1], f0, oacc[1][0]);
      oacc[1][1] = MFMA16(ap[1], f1, oacc[1][1]);
    }
    __builtin_amdgcn_s_setprio(0);
  };

  S_phase(0, 0);
  int buf = 0;
  for (int t = 0; t < 16; ++t) {
    __syncthreads();
    int j0 = t * 256;
    bf16x8 fvp[2][4];
#pragma unroll
    for (int cs = 0; cs < 2; ++cs)
#pragma unroll
      for (int h = 0; h < 4; ++h)
        fvp[cs][h] = ld8(vf + (((2 * cw + cs) * 128 + (j0 >> 5) + h) << 9) + lane * 8);
    if (wid & 1) {
      if (t < 15) S_phase(j0 + 256, buf ^ 1);
      PV_phase(j0, buf, fvp);
    } else {
      PV_phase(j0, buf, fvp);
      if (t < 15) S_phase(j0 + 256, buf ^ 1);
    }
    buf ^= 1;
  }

  // ---- fused MLP on the block's 64x256 tile ----
  u16 (*attL)[264] = P[0];  // att tile (P dead after j-loop)
  u16 (*hdnL)[264] = P[1];  // hdn tile
  __syncthreads();  // all PV reads of P complete
#pragma unroll
  for (int m = 0; m < 2; ++m)
#pragma unroll
    for (int cs = 0; cs < 2; ++cs)
#pragma unroll
      for (int r = 0; r < 4; ++r)
        attL[32 * ih + 16 * m + 4 * g + r][32 * cw + 16 * cs + l15] =
            f2bf(oacc[m][cs][r]);
  __syncthreads();

  // stage 1: hdn = mish(att @ W1^T + b1); wave strip = 16 h (ostrip = wid)
  {
    f32x4 acc1[4];
#pragma unroll
    for (int m = 0; m < 4; ++m) acc1[m] = fz4();
    for (int kk = 0; kk < 8; ++kk) {
      bf16x8 bn = ld8(w1 + ((wid * 8 + kk) << 9) + lane * 8);
#pragma unroll
      for (int m = 0; m < 4; ++m) {
        bf16x8 am = ld8(&attL[16 * m + l15][kk * 32 + 8 * g]);
        acc1[m] = MFMA16(am, bn, acc1[m]);
      }
    }
    float bb = b1[16 * wid + l15];
#pragma unroll
    for (int m = 0; m < 4; ++m)
#pragma unroll
      for (int r = 0; r < 4; ++r) {
        float v = acc1[m][r] + bb;
        float sp = (v > 15.f) ? v : __logf(1.f + __expf(v));
        float e2 = __expf(-2.f * sp);
        float th = (1.f - e2) / (1.f + e2);
        hdnL[16 * m + 4 * g + r][16 * wid + l15] = f2bf(v * th);
      }
  }
  __syncthreads();

  // stage 2: out = hdn @ W2^T + b2 + x; wave strip = 16 o (ostrip = wid)
  {
    f32x4 acc2[4];
#pragma unroll
    for (int n = 0; n < 4; ++n) acc2[n] = fz4();
    for (int kk = 0; kk < 8; ++kk) {
      bf16x8 am = ld8(w2 + ((wid * 8 + kk) << 9) + lane * 8);
#pragma unroll
      for (int n = 0; n < 4; ++n) {
        bf16x8 bn = ld8(&hdnL[16 * n + l15][kk * 32 + 8 * g]);
        acc2[n] = MFMA16(am, bn, acc2[n]);
      }
    }
    f32x4 b2v = *reinterpret_cast<const f32x4*>(b2 + 16 * wid + 4 * g);
#pragma unroll
    for (int r = 0; r < 4; ++r) {
      int o = 16 * wid + 4 * g + r;
#pragma unroll
      for (int n = 0; n < 4; ++n) {
        int pos = i0 + 16 * n + l15;
        size_t idx = ((size_t)b * 256 + o) * 4096 + pos;
        out[idx] = acc2[n][r] + b2v[r] + x[idx];
      }
    }
  }
}

// ---- workspace layout (bytes) ---------------------------------------------
#define WS_XT 0u          //  8,388,608  xTf  [4][256*8][64][8] bf16
#define WS_QT 8388608u    //  2,097,152  Qf  [4][256*2][64][8] bf16
#define WS_KT 10485760u   //  2,097,152  Kf  [4][256*2][64][8] bf16
#define WS_VC 12582912u   //  8,388,608  Vf  [4][16*128][64][8] bf16
#define WS_WQ 21037056u   //     32,768  wqf [4*8][64][8]
#define WS_WK 21069824u   //     32,768
#define WS_WV 21102592u   //    131,072  wvf [16*8][64][8]
#define WS_W1 21233664u   //    131,072
#define WS_W2 21364736u   //    131,072   (end: 21,495,808 < 29,884,416)

extern "C" void kernel_launch(void* const* d_in, const int* in_sizes, int n_in,
                              void* d_out, int out_size, void* d_ws, size_t ws_size,
                              hipStream_t stream) {
  (void)in_sizes; (void)n_in; (void)out_size; (void)ws_size;
  const float* x  = (const float*)d_in[0];
  const float* WQ = (const float*)d_in[1];
  const float* bQ = (const float*)d_in[2];
  const float* WK = (const float*)d_in[3];
  const float* bK = (const float*)d_in[4];
  const float* WV = (const float*)d_in[5];
  const float* bV = (const float*)d_in[6];
  const float* PE = (const float*)d_in[7];
  const float* W1 = (const float*)d_in[8];
  const float* b1 = (const float*)d_in[9];
  const float* W2 = (const float*)d_in[10];
  const float* b2 = (const float*)d_in[11];
  float* out = (float*)d_out;
  char* ws = (char*)d_ws;

  u16* xT   = (u16*)(ws + WS_XT);
  u16* Qt   = (u16*)(ws + WS_QT);
  u16* Kt   = (u16*)(ws + WS_KT);
  u16* Vc   = (u16*)(ws + WS_VC);
  u16* wqB  = (u16*)(ws + WS_WQ);
  u16* wkB  = (u16*)(ws + WS_WK);
  u16* wvB  = (u16*)(ws + WS_WV);
  u16* w1B  = (u16*)(ws + WS_W1);
  u16* w2B  = (u16*)(ws + WS_W2);

  k_prep<<<1136, 256, 0, stream>>>(x, WQ, WK, WV, W1, W2, xT, wqB, wkB, wvB, w1B, w2B);
  k_proj<<<512, 256, 0, stream>>>(xT, wqB, wkB, wvB, bQ, bK, bV, PE, Qt, Kt, Vc);
  k_colsum<<<256, 512, 0, stream>>>(Qt, Kt, Vc);
  k_attn<<<256, 1024, 0, stream>>>(Qt, Kt, Vc, w1B, b1, w2B, b2, x, out);
}